// Round 1
// baseline (481.804 us; speedup 1.0000x reference)
//
#include <hip/hip_runtime.h>
#include <cstdint>

#define HH 128
#define WW 128
#define CC 64
#define BB 16
#define PLANE (HH*WW)

// ---------------------------------------------------------------------------
// Kernel 1: U = x + avg3(x) + max3(x)
// avg: count_include_pad (sum/9, zero pad). max: over valid taps only.
// ---------------------------------------------------------------------------
__global__ __launch_bounds__(256) void k_pool(const float* __restrict__ x,
                                              float* __restrict__ U) {
  int idx = blockIdx.x * 256 + threadIdx.x;
  int w = idx & (WW - 1);
  int h = (idx >> 7) & (HH - 1);
  int pl = idx >> 14;
  const float* xp = x + (size_t)pl * PLANE;
  float c = xp[h * WW + w];
  float s = 0.f, m = -3.402823466e+38f;
  #pragma unroll
  for (int dr = -1; dr <= 1; ++dr) {
    int r = h + dr;
    if (r < 0 || r >= HH) continue;
    #pragma unroll
    for (int dc = -1; dc <= 1; ++dc) {
      int cc = w + dc;
      if (cc < 0 || cc >= WW) continue;
      float v = xp[r * WW + cc];
      s += v;
      m = fmaxf(m, v);
    }
  }
  U[idx] = c + s * (1.f / 9.f) + m;
}

// ---------------------------------------------------------------------------
// Kernel 2: T = dw5x5(U) + sep7(U) + sep11(U) + sep21(U), biases tripled.
// Tile: 64 rows x 32 cols per block. LDS: x tile with halo 10, plus
// horizontal intermediates h7/h11/h21 over 84 halo rows.
// Two-pass separable with explicit zero h-rows outside the image reproduces
// the reference's zero-padded-intermediate boundary semantics exactly.
// ---------------------------------------------------------------------------
__global__ __launch_bounds__(256) void k_dwsum(
    const float* __restrict__ U, float* __restrict__ T,
    const float* __restrict__ w55, const float* __restrict__ b55,
    const float* __restrict__ w17_0, const float* __restrict__ b17_0,
    const float* __restrict__ w17_1, const float* __restrict__ b17_1,
    const float* __restrict__ w111_0, const float* __restrict__ b111_0,
    const float* __restrict__ w111_1, const float* __restrict__ b111_1,
    const float* __restrict__ w211_0, const float* __restrict__ b211_0,
    const float* __restrict__ w211_1, const float* __restrict__ b211_1) {
  __shared__ float xs[84][56];    // rows tR0-10..tR0+73, cols tC0-10..tC0+41 (52 used)
  __shared__ float h7s[84][36];   // 32 cols used
  __shared__ float h11s[84][36];
  __shared__ float h21s[84][36];

  int bid = blockIdx.x;
  int pl = bid >> 3;
  int t = bid & 7;
  int tR0 = (t >> 2) * 64;
  int tC0 = (t & 3) * 32;
  int ch = pl & (CC - 1);
  const float* Up = U + (size_t)pl * PLANE;
  float* Tp = T + (size_t)pl * PLANE;
  int tid = threadIdx.x;

  // ---- load x tile (zero OOB) ----
  for (int i = tid; i < 84 * 52; i += 256) {
    int tr = i / 52;
    int tc = i - tr * 52;
    int gr = tR0 - 10 + tr;
    int gc = tC0 - 10 + tc;
    float v = 0.f;
    if ((unsigned)gr < (unsigned)HH && (unsigned)gc < (unsigned)WW)
      v = Up[gr * WW + gc];
    xs[tr][tc] = v;
  }

  // horizontal weights (per-channel)
  float k7[7], k11[11], k21[21];
  #pragma unroll
  for (int i = 0; i < 7; ++i) k7[i] = w17_0[ch * 7 + i];
  #pragma unroll
  for (int i = 0; i < 11; ++i) k11[i] = w111_0[ch * 11 + i];
  #pragma unroll
  for (int i = 0; i < 21; ++i) k21[i] = w211_0[ch * 21 + i];
  float bb7 = 3.f * b17_0[ch];
  float bb11 = 3.f * b111_0[ch];
  float bb21 = 3.f * b211_0[ch];

  __syncthreads();

  // ---- phase B: horizontal passes at all 84 halo rows, 8 col-groups of 4 ----
  for (int i = tid; i < 84 * 8; i += 256) {
    int tr = i >> 3;
    int cg = i & 7;
    const float* xrow = &xs[tr][cg * 4];
    float win[24];
    #pragma unroll
    for (int j = 0; j < 6; ++j) {
      float4 v = *(const float4*)(xrow + 4 * j);
      win[4 * j + 0] = v.x; win[4 * j + 1] = v.y;
      win[4 * j + 2] = v.z; win[4 * j + 3] = v.w;
    }
    int gr = tR0 - 10 + tr;
    bool rv = ((unsigned)gr < (unsigned)HH);
    float o7[4], o11[4], o21[4];
    #pragma unroll
    for (int j = 0; j < 4; ++j) {
      float a7 = bb7, a11 = bb11, a21 = bb21;
      #pragma unroll
      for (int d = 0; d < 7; ++d) a7 += k7[d] * win[j + 7 + d];
      #pragma unroll
      for (int d = 0; d < 11; ++d) a11 += k11[d] * win[j + 5 + d];
      #pragma unroll
      for (int d = 0; d < 21; ++d) a21 += k21[d] * win[j + d];
      o7[j] = rv ? a7 : 0.f;
      o11[j] = rv ? a11 : 0.f;
      o21[j] = rv ? a21 : 0.f;
    }
    *(float4*)&h7s[tr][cg * 4] = make_float4(o7[0], o7[1], o7[2], o7[3]);
    *(float4*)&h11s[tr][cg * 4] = make_float4(o11[0], o11[1], o11[2], o11[3]);
    *(float4*)&h21s[tr][cg * 4] = make_float4(o21[0], o21[1], o21[2], o21[3]);
  }

  // vertical + 5x5 weights
  float v7[7], v11[11], v21[21], w5[25];
  #pragma unroll
  for (int i = 0; i < 7; ++i) v7[i] = w17_1[ch * 7 + i];
  #pragma unroll
  for (int i = 0; i < 11; ++i) v11[i] = w111_1[ch * 11 + i];
  #pragma unroll
  for (int i = 0; i < 21; ++i) v21[i] = w211_1[ch * 21 + i];
  #pragma unroll
  for (int i = 0; i < 25; ++i) w5[i] = w55[ch * 25 + i];
  float bsum = 3.f * (b55[ch] + b17_1[ch] + b111_1[ch] + b211_1[ch]);

  __syncthreads();

  // ---- phase C: vertical passes + 5x5, 64 rows x 8 col-groups ----
  for (int i = tid; i < 64 * 8; i += 256) {
    int r = i >> 3;
    int cg = i & 7;
    float acc[4] = {bsum, bsum, bsum, bsum};
    // 5x5 direct on U
    #pragma unroll
    for (int dr = 0; dr < 5; ++dr) {
      const float* row = &xs[r + dr + 8][cg * 4 + 8];
      float4 xa = *(const float4*)row;
      float4 xb = *(const float4*)(row + 4);
      float xw[8] = {xa.x, xa.y, xa.z, xa.w, xb.x, xb.y, xb.z, xb.w};
      #pragma unroll
      for (int j = 0; j < 4; ++j) {
        #pragma unroll
        for (int dc = 0; dc < 5; ++dc) acc[j] += w5[dr * 5 + dc] * xw[j + dc];
      }
    }
    // vertical 7
    #pragma unroll
    for (int d = 0; d < 7; ++d) {
      float4 hv = *(const float4*)&h7s[r + d + 7][cg * 4];
      acc[0] += v7[d] * hv.x; acc[1] += v7[d] * hv.y;
      acc[2] += v7[d] * hv.z; acc[3] += v7[d] * hv.w;
    }
    // vertical 11
    #pragma unroll
    for (int d = 0; d < 11; ++d) {
      float4 hv = *(const float4*)&h11s[r + d + 5][cg * 4];
      acc[0] += v11[d] * hv.x; acc[1] += v11[d] * hv.y;
      acc[2] += v11[d] * hv.z; acc[3] += v11[d] * hv.w;
    }
    // vertical 21
    #pragma unroll
    for (int d = 0; d < 21; ++d) {
      float4 hv = *(const float4*)&h21s[r + d][cg * 4];
      acc[0] += v21[d] * hv.x; acc[1] += v21[d] * hv.y;
      acc[2] += v21[d] * hv.z; acc[3] += v21[d] * hv.w;
    }
    *(float4*)(Tp + (size_t)(tR0 + r) * WW + tC0 + cg * 4) =
        make_float4(acc[0], acc[1], acc[2], acc[3]);
  }
}

// ---------------------------------------------------------------------------
// Kernel 3: out = (W11 . T + 3*b11) * x   (per-pixel 64x64 matvec)
// Tile: 64 pixels x 64 co, K=64. Both operands staged in LDS.
// ---------------------------------------------------------------------------
__global__ __launch_bounds__(256) void k_mix(const float* __restrict__ T,
                                             const float* __restrict__ x,
                                             const float* __restrict__ w11,
                                             const float* __restrict__ b11,
                                             float* __restrict__ out) {
  __shared__ float Tl[64][64];  // [ci][px]
  __shared__ float Wt[64][64];  // [ci][co]
  int bid = blockIdx.x;
  int b = bid >> 8;
  int px0 = (bid & 255) * 64;
  const float* Tb = T + (size_t)b * (CC * PLANE) + px0;
  const float* xb = x + (size_t)b * (CC * PLANE) + px0;
  float* ob = out + (size_t)b * (CC * PLANE) + px0;
  int tid = threadIdx.x;

  // load W transposed: Wt[ci][co] = w11[co*64+ci]
  for (int i = tid; i < 4096; i += 256) {
    int ci = i >> 6;
    int co = i & 63;
    Wt[ci][co] = w11[co * 64 + ci];
  }
  // load T tile
  #pragma unroll
  for (int j = 0; j < 4; ++j) {
    int i = j * 256 + tid;
    int ci = i >> 4;
    int c4 = i & 15;
    *(float4*)&Tl[ci][c4 * 4] =
        *(const float4*)(Tb + (size_t)ci * PLANE + c4 * 4);
  }
  __syncthreads();

  int p4 = tid & 15;   // pixel group: px p4*4..+3
  int cg = tid >> 4;   // co group:    co cg*4..+3
  float acc[4][4];     // [co][px]
  #pragma unroll
  for (int a = 0; a < 4; ++a)
    #pragma unroll
    for (int q = 0; q < 4; ++q) acc[a][q] = 0.f;

  #pragma unroll 8
  for (int k = 0; k < 64; ++k) {
    float4 wv = *(const float4*)&Wt[k][cg * 4];
    float4 tv = *(const float4*)&Tl[k][p4 * 4];
    acc[0][0] += wv.x * tv.x; acc[0][1] += wv.x * tv.y;
    acc[0][2] += wv.x * tv.z; acc[0][3] += wv.x * tv.w;
    acc[1][0] += wv.y * tv.x; acc[1][1] += wv.y * tv.y;
    acc[1][2] += wv.y * tv.z; acc[1][3] += wv.y * tv.w;
    acc[2][0] += wv.z * tv.x; acc[2][1] += wv.z * tv.y;
    acc[2][2] += wv.z * tv.z; acc[2][3] += wv.z * tv.w;
    acc[3][0] += wv.w * tv.x; acc[3][1] += wv.w * tv.y;
    acc[3][2] += wv.w * tv.z; acc[3][3] += wv.w * tv.w;
  }

  #pragma unroll
  for (int jc = 0; jc < 4; ++jc) {
    int co = cg * 4 + jc;
    float bb = 3.f * b11[co];
    float4 xv = *(const float4*)(xb + (size_t)co * PLANE + p4 * 4);
    float4 o;
    o.x = (acc[jc][0] + bb) * xv.x;
    o.y = (acc[jc][1] + bb) * xv.y;
    o.z = (acc[jc][2] + bb) * xv.z;
    o.w = (acc[jc][3] + bb) * xv.w;
    *(float4*)(ob + (size_t)co * PLANE + p4 * 4) = o;
  }
}

extern "C" void kernel_launch(void* const* d_in, const int* in_sizes, int n_in,
                              void* d_out, int out_size, void* d_ws,
                              size_t ws_size, hipStream_t stream) {
  const float* x = (const float*)d_in[0];
  const float* w55 = (const float*)d_in[1];
  const float* b55 = (const float*)d_in[2];
  const float* w17_0 = (const float*)d_in[3];
  const float* b17_0 = (const float*)d_in[4];
  const float* w17_1 = (const float*)d_in[5];
  const float* b17_1 = (const float*)d_in[6];
  const float* w111_0 = (const float*)d_in[7];
  const float* b111_0 = (const float*)d_in[8];
  const float* w111_1 = (const float*)d_in[9];
  const float* b111_1 = (const float*)d_in[10];
  const float* w211_0 = (const float*)d_in[11];
  const float* b211_0 = (const float*)d_in[12];
  const float* w211_1 = (const float*)d_in[13];
  const float* b211_1 = (const float*)d_in[14];
  const float* w11 = (const float*)d_in[15];
  const float* b11 = (const float*)d_in[16];
  float* outp = (float*)d_out;

  float* U = (float*)d_ws;                      // [16,64,128,128]
  float* T = U + (size_t)BB * CC * PLANE;       // [16,64,128,128]

  k_pool<<<(BB * CC * PLANE) / 256, 256, 0, stream>>>(x, U);
  k_dwsum<<<BB * CC * 8, 256, 0, stream>>>(
      U, T, w55, b55, w17_0, b17_0, w17_1, b17_1, w111_0, b111_0, w111_1,
      b111_1, w211_0, b211_0, w211_1, b211_1);
  k_mix<<<BB * 256, 256, 0, stream>>>(T, x, w11, b11, outp);
}

// Round 2
// 331.863 us; speedup vs baseline: 1.4518x; 1.4518x over previous
//
#include <hip/hip_runtime.h>
#include <cstdint>

#define HH 128
#define WW 128
#define CC 64
#define BB 16
#define PLANE (HH*WW)

// ---------------------------------------------------------------------------
// k_dwsum: fused  U = x + avg3(x) + max3(x)  ->  T = dw5x5(U) + sep7(U) +
// sep11(U) + sep21(U)  (all biases tripled; boundary semantics exact).
//
// Tile 64 rows x 32 cols. LDS layout (floats), strides chosen mod 32 in
// {4,12,28} so 64-lane b128 reads form a complete bank partition:
//   xs  [84][60]  U row-major, rows -10..73, cols -10..41      (phase B input)
//   xsT [36][68]  U col-major, cols -2..33,  rows -2..65       (5x5 in phase C)
//   h7T [32][76]  col-major horiz-7 result, rows -3..66
//   union {  xraw [86][60] raw x rows -11..74 cols -12..43 (phase A only)
//          | h11T [32][76] rows -5..68 ; h21T [32][92] rows -10..73 }
// ---------------------------------------------------------------------------
#define XS_OFF    0
#define XS_STR    60
#define XST_OFF   5040
#define XST_STR   68
#define H7_OFF    7488
#define H7_STR    76
#define UNION_OFF 9920
#define XRAW_STR  60
#define H11_OFF   UNION_OFF
#define H11_STR   76
#define H21_OFF   (UNION_OFF + 2432)
#define H21_STR   92
#define SMEM_FLOATS 15296   // 61184 B -> 2 blocks/CU

__global__ __launch_bounds__(256) void k_dwsum(
    const float* __restrict__ x, float* __restrict__ T,
    const float* __restrict__ w55, const float* __restrict__ b55,
    const float* __restrict__ w17_0, const float* __restrict__ b17_0,
    const float* __restrict__ w17_1, const float* __restrict__ b17_1,
    const float* __restrict__ w111_0, const float* __restrict__ b111_0,
    const float* __restrict__ w111_1, const float* __restrict__ b111_1,
    const float* __restrict__ w211_0, const float* __restrict__ b211_0,
    const float* __restrict__ w211_1, const float* __restrict__ b211_1) {
  __shared__ float sm[SMEM_FLOATS];

  const int bid = blockIdx.x;
  const int pl = bid >> 3;                 // (batch, channel) plane
  const int t = bid & 7;
  const int tR0 = (t >> 2) * 64;
  const int tC0 = (t & 3) * 32;
  const int ch = pl & (CC - 1);
  const float* xp = x + (size_t)pl * PLANE;
  float* Tp = T + (size_t)pl * PLANE;
  const int tid = threadIdx.x;

  // ---- phase A: load raw x tile (halo 11/12), zero OOB ----
  {
    float* xraw = sm + UNION_OFF;
    const int base_r = tR0 - 11, base_c = tC0 - 12;
    for (int i = tid; i < 86 * 14; i += 256) {
      int rr = i / 14;
      int jj = i - rr * 14;
      int gr = base_r + rr;
      int gc = base_c + jj * 4;            // 4-aligned; whole float4 in or out
      float4 v = make_float4(0.f, 0.f, 0.f, 0.f);
      if ((unsigned)gr < 128u && (unsigned)gc < 128u)
        v = *(const float4*)(xp + gr * WW + gc);
      *(float4*)(xraw + rr * XRAW_STR + jj * 4) = v;
    }
  }
  __syncthreads();

  // ---- phase A2: U = x + avg3 + max3 over rows -10..73, cols -10..41 ----
  {
    const float* xraw = sm + UNION_OFF;
    for (int i = tid; i < 84 * 13; i += 256) {
      int rr = i / 13;                     // xs row (tile row rr-10)
      int jj = i - rr * 13;                // col chunk: tile cols 4jj-10..+3
      const float* rp = xraw + rr * XRAW_STR + jj * 4;
      float4 a0 = *(const float4*)(rp);
      float4 a1 = *(const float4*)(rp + 4);
      float4 b0 = *(const float4*)(rp + XRAW_STR);
      float4 b1 = *(const float4*)(rp + XRAW_STR + 4);
      float4 c0 = *(const float4*)(rp + 2 * XRAW_STR);
      float4 c1 = *(const float4*)(rp + 2 * XRAW_STR + 4);
      float w0[8] = {a0.x, a0.y, a0.z, a0.w, a1.x, a1.y, a1.z, a1.w};
      float w1[8] = {b0.x, b0.y, b0.z, b0.w, b1.x, b1.y, b1.z, b1.w};
      float w2[8] = {c0.x, c0.y, c0.z, c0.w, c1.x, c1.y, c1.z, c1.w};
      int gr = tR0 + rr - 10;
      bool rv0 = (unsigned)(gr - 1) < 128u;
      bool rv1 = (unsigned)(gr) < 128u;
      bool rv2 = (unsigned)(gr + 1) < 128u;
      int gc0 = tC0 + jj * 4 - 12;         // global col of window pos 0
      float M0[8], M1[8], M2[8];
      #pragma unroll
      for (int p = 1; p <= 6; ++p) {
        bool cv = (unsigned)(gc0 + p) < 128u;
        M0[p] = (rv0 && cv) ? w0[p] : -3.402823466e38f;
        M1[p] = (rv1 && cv) ? w1[p] : -3.402823466e38f;
        M2[p] = (rv2 && cv) ? w2[p] : -3.402823466e38f;
      }
      float uq[4];
      #pragma unroll
      for (int q = 0; q < 4; ++q) {
        float s = w0[q + 1] + w0[q + 2] + w0[q + 3] + w1[q + 1] + w1[q + 2] +
                  w1[q + 3] + w2[q + 1] + w2[q + 2] + w2[q + 3];
        float m = fmaxf(
            fmaxf(fmaxf(M0[q + 1], M0[q + 2]), fmaxf(M0[q + 3], M1[q + 1])),
            fmaxf(fmaxf(M1[q + 2], M1[q + 3]),
                  fmaxf(fmaxf(M2[q + 1], M2[q + 2]), M2[q + 3])));
        float val = w1[q + 2] + s * (1.f / 9.f) + m;
        bool vo = rv1 && ((unsigned)(gc0 + q + 2) < 128u);
        uq[q] = vo ? val : 0.f;
      }
      *(float4*)(sm + XS_OFF + rr * XS_STR + jj * 4) =
          make_float4(uq[0], uq[1], uq[2], uq[3]);
      int rt = rr - 8;                     // xsT row idx
      if ((unsigned)rt < 68u) {
        #pragma unroll
        for (int q = 0; q < 4; ++q) {
          int ct = jj * 4 + q - 8;         // xsT col idx
          if ((unsigned)ct < 36u) sm[XST_OFF + ct * XST_STR + rt] = uq[q];
        }
      }
    }
  }

  // horizontal weights (wave-uniform ch -> scalar loads)
  float k7[7], k11[11], k21[21];
  #pragma unroll
  for (int i = 0; i < 7; ++i) k7[i] = w17_0[ch * 7 + i];
  #pragma unroll
  for (int i = 0; i < 11; ++i) k11[i] = w111_0[ch * 11 + i];
  #pragma unroll
  for (int i = 0; i < 21; ++i) k21[i] = w211_0[ch * 21 + i];
  float bb7 = 3.f * b17_0[ch];
  float bb11 = 3.f * b111_0[ch];
  float bb21 = 3.f * b211_0[ch];

  __syncthreads();

  // ---- phase B: horizontal convs, 8 outputs along c, transposed stores ----
  for (int it = tid; it < 84 * 4; it += 256) {
    int rr = it >> 2;                      // xs row (tile row rr-10)
    int cg = it & 3;                       // output tile cols cg*8..+7
    float w[28];
    const float* xr = sm + XS_OFF + rr * XS_STR + cg * 8;
    #pragma unroll
    for (int j = 0; j < 7; ++j) {
      float4 v = *(const float4*)(xr + 4 * j);
      w[4 * j] = v.x; w[4 * j + 1] = v.y; w[4 * j + 2] = v.z; w[4 * j + 3] = v.w;
    }
    int gr = tR0 + rr - 10;
    bool rv = (unsigned)gr < 128u;
    bool v11r = (rr >= 5) && (rr <= 78);
    bool v7r = (rr >= 7) && (rr <= 76);
    #pragma unroll
    for (int j = 0; j < 8; ++j) {
      float a21 = bb21, a11 = bb11, a7 = bb7;
      #pragma unroll
      for (int d = 0; d < 21; ++d) a21 += k21[d] * w[j + d];
      #pragma unroll
      for (int d = 0; d < 11; ++d) a11 += k11[d] * w[j + 5 + d];
      #pragma unroll
      for (int d = 0; d < 7; ++d) a7 += k7[d] * w[j + 7 + d];
      int c = cg * 8 + j;
      sm[H21_OFF + c * H21_STR + rr] = rv ? a21 : 0.f;
      if (v11r) sm[H11_OFF + c * H11_STR + rr - 5] = rv ? a11 : 0.f;
      if (v7r) sm[H7_OFF + c * H7_STR + rr - 7] = rv ? a7 : 0.f;
    }
  }

  // vertical + 5x5 weights
  float v7a[7], v11a[11], v21a[21], w5a[25];
  #pragma unroll
  for (int i = 0; i < 7; ++i) v7a[i] = w17_1[ch * 7 + i];
  #pragma unroll
  for (int i = 0; i < 11; ++i) v11a[i] = w111_1[ch * 11 + i];
  #pragma unroll
  for (int i = 0; i < 21; ++i) v21a[i] = w211_1[ch * 21 + i];
  #pragma unroll
  for (int i = 0; i < 25; ++i) w5a[i] = w55[ch * 25 + i];
  float bsum = 3.f * (b55[ch] + b17_1[ch] + b111_1[ch] + b211_1[ch]);

  __syncthreads();

  // ---- phase C: vertical convs + 5x5, 8 outputs along r per thread ----
  {
    int c = tid & 31;
    int r0 = (tid >> 5) * 8;
    float acc[8];
    #pragma unroll
    for (int j = 0; j < 8; ++j) acc[j] = bsum;

    float A[28];
    {
      const float* hp = sm + H21_OFF + c * H21_STR + r0;
      #pragma unroll
      for (int j = 0; j < 7; ++j) {
        float4 v = *(const float4*)(hp + 4 * j);
        A[4 * j] = v.x; A[4 * j + 1] = v.y; A[4 * j + 2] = v.z; A[4 * j + 3] = v.w;
      }
      #pragma unroll
      for (int d = 0; d < 21; ++d)
        #pragma unroll
        for (int j = 0; j < 8; ++j) acc[j] += v21a[d] * A[d + j];
    }
    {
      const float* hp = sm + H11_OFF + c * H11_STR + r0;
      #pragma unroll
      for (int j = 0; j < 5; ++j) {
        float4 v = *(const float4*)(hp + 4 * j);
        A[4 * j] = v.x; A[4 * j + 1] = v.y; A[4 * j + 2] = v.z; A[4 * j + 3] = v.w;
      }
      #pragma unroll
      for (int d = 0; d < 11; ++d)
        #pragma unroll
        for (int j = 0; j < 8; ++j) acc[j] += v11a[d] * A[d + j];
    }
    {
      const float* hp = sm + H7_OFF + c * H7_STR + r0;
      #pragma unroll
      for (int j = 0; j < 4; ++j) {
        float4 v = *(const float4*)(hp + 4 * j);
        A[4 * j] = v.x; A[4 * j + 1] = v.y; A[4 * j + 2] = v.z; A[4 * j + 3] = v.w;
      }
      #pragma unroll
      for (int d = 0; d < 7; ++d)
        #pragma unroll
        for (int j = 0; j < 8; ++j) acc[j] += v7a[d] * A[d + j];
    }
    #pragma unroll
    for (int dc = 0; dc < 5; ++dc) {
      const float* hp = sm + XST_OFF + (c + dc) * XST_STR + r0;
      float X[12];
      #pragma unroll
      for (int j = 0; j < 3; ++j) {
        float4 v = *(const float4*)(hp + 4 * j);
        X[4 * j] = v.x; X[4 * j + 1] = v.y; X[4 * j + 2] = v.z; X[4 * j + 3] = v.w;
      }
      #pragma unroll
      for (int dr = 0; dr < 5; ++dr)
        #pragma unroll
        for (int j = 0; j < 8; ++j) acc[j] += w5a[dr * 5 + dc] * X[j + dr];
    }
    #pragma unroll
    for (int j = 0; j < 8; ++j)
      Tp[(size_t)(tR0 + r0 + j) * WW + tC0 + c] = acc[j];
  }
}

// ---------------------------------------------------------------------------
// k_mix: out = (W11 . T + 3*b11) * x.  T read straight from global (read
// exactly once, L3-resident); only W (transposed, 17 KB) staged in LDS.
// Block: 256 threads = 256 px x 64 co tile, 8x8 per thread.
// ---------------------------------------------------------------------------
__global__ __launch_bounds__(256) void k_mix(const float* __restrict__ T,
                                             const float* __restrict__ x,
                                             const float* __restrict__ w11,
                                             const float* __restrict__ b11,
                                             float* __restrict__ out) {
  __shared__ float Wt[64 * 68];            // [ci][co], stride 68
  int bid = blockIdx.x;
  int b = bid >> 6;
  int px0 = (bid & 63) * 256;
  int tid = threadIdx.x;

  for (int i = tid; i < 4096; i += 256) {
    int co = i >> 6, ci = i & 63;
    Wt[ci * 68 + co] = w11[i];
  }
  __syncthreads();

  int pxg = tid & 31;                      // 32 groups x 8 px
  int cog = tid >> 5;                      // 8 groups x 8 co
  const float* Tb = T + (size_t)b * (CC * PLANE) + px0 + pxg * 8;
  const float* wrow = Wt + cog * 8;

  float acc[8][8];                         // [co][px]
  #pragma unroll
  for (int a = 0; a < 8; ++a)
    #pragma unroll
    for (int p = 0; p < 8; ++p) acc[a][p] = 0.f;

  #pragma unroll 4
  for (int k = 0; k < 64; ++k) {
    float4 t0 = *(const float4*)(Tb + (size_t)k * PLANE);
    float4 t1 = *(const float4*)(Tb + (size_t)k * PLANE + 4);
    float4 q0 = *(const float4*)(wrow + k * 68);
    float4 q1 = *(const float4*)(wrow + k * 68 + 4);
    float tv[8] = {t0.x, t0.y, t0.z, t0.w, t1.x, t1.y, t1.z, t1.w};
    float wf[8] = {q0.x, q0.y, q0.z, q0.w, q1.x, q1.y, q1.z, q1.w};
    #pragma unroll
    for (int a = 0; a < 8; ++a)
      #pragma unroll
      for (int p = 0; p < 8; ++p) acc[a][p] += wf[a] * tv[p];
  }

  const float* xb = x + (size_t)b * (CC * PLANE) + px0 + pxg * 8;
  float* ob = out + (size_t)b * (CC * PLANE) + px0 + pxg * 8;
  #pragma unroll
  for (int a = 0; a < 8; ++a) {
    int co = cog * 8 + a;
    float bb = 3.f * b11[co];
    const float* xr = xb + (size_t)co * PLANE;
    float* orow = ob + (size_t)co * PLANE;
    float4 x0 = *(const float4*)(xr);
    float4 x1 = *(const float4*)(xr + 4);
    float4 o0, o1;
    o0.x = (acc[a][0] + bb) * x0.x; o0.y = (acc[a][1] + bb) * x0.y;
    o0.z = (acc[a][2] + bb) * x0.z; o0.w = (acc[a][3] + bb) * x0.w;
    o1.x = (acc[a][4] + bb) * x1.x; o1.y = (acc[a][5] + bb) * x1.y;
    o1.z = (acc[a][6] + bb) * x1.z; o1.w = (acc[a][7] + bb) * x1.w;
    *(float4*)(orow) = o0;
    *(float4*)(orow + 4) = o1;
  }
}

extern "C" void kernel_launch(void* const* d_in, const int* in_sizes, int n_in,
                              void* d_out, int out_size, void* d_ws,
                              size_t ws_size, hipStream_t stream) {
  const float* x = (const float*)d_in[0];
  const float* w55 = (const float*)d_in[1];
  const float* b55 = (const float*)d_in[2];
  const float* w17_0 = (const float*)d_in[3];
  const float* b17_0 = (const float*)d_in[4];
  const float* w17_1 = (const float*)d_in[5];
  const float* b17_1 = (const float*)d_in[6];
  const float* w111_0 = (const float*)d_in[7];
  const float* b111_0 = (const float*)d_in[8];
  const float* w111_1 = (const float*)d_in[9];
  const float* b111_1 = (const float*)d_in[10];
  const float* w211_0 = (const float*)d_in[11];
  const float* b211_0 = (const float*)d_in[12];
  const float* w211_1 = (const float*)d_in[13];
  const float* b211_1 = (const float*)d_in[14];
  const float* w11 = (const float*)d_in[15];
  const float* b11 = (const float*)d_in[16];
  float* outp = (float*)d_out;

  float* T = (float*)d_ws;                 // [16,64,128,128]

  k_dwsum<<<BB * CC * 8, 256, 0, stream>>>(
      x, T, w55, b55, w17_0, b17_0, w17_1, b17_1, w111_0, b111_0, w111_1,
      b111_1, w211_0, b211_0, w211_1, b211_1);
  k_mix<<<BB * 64, 256, 0, stream>>>(T, x, w11, b11, outp);
}

// Round 3
// 306.574 us; speedup vs baseline: 1.5716x; 1.0825x over previous
//
#include <hip/hip_runtime.h>
#include <hip/hip_bf16.h>
#include <cstdint>

#define HH 128
#define WW 128
#define CC 64
#define BB 16
#define PLANE (HH*WW)

// LDS layout (floats). Strides chosen so phase-C b128 column reads tile the
// 32 banks (stride mod 8 == 4 or 2-way-free mod 8 == 0):
//   xs   [84][56]  U row-major, rows -10..73, cols -10..41 (52 used)
//   xsTh [36][72]  U col-major in BF16 (halves), cols -2..33, rows -2..65
//   h7T  [32][72]  rows -3..66 (70 used)
//   union { xraw [86][56] (phase A) | h11T [32][76] rows -5..68 ;
//           h21T [32][84] rows -10..73 }
#define XS_OFF    0
#define XS_STR    56
#define XSTH_OFF  4704        // bf16, stride 72 halves, 36*72 halves = 1296 floats
#define H7_OFF    6000
#define H7_STR    72
#define UNION_OFF 8304
#define XRAW_STR  56
#define H11_OFF   UNION_OFF
#define H11_STR   76
#define H21_OFF   (UNION_OFF + 2432)
#define H21_STR   84
#define SMEM_FLOATS 13424     // 53696 B -> 3 blocks/CU

__device__ __forceinline__ float lo16(unsigned int u) {
  return __uint_as_float(u << 16);
}
__device__ __forceinline__ float hi16(unsigned int u) {
  return __uint_as_float(u & 0xffff0000u);
}

__global__ __launch_bounds__(256, 3) void k_dwsum(
    const float* __restrict__ x, float* __restrict__ T,
    const float* __restrict__ w55, const float* __restrict__ b55,
    const float* __restrict__ w17_0, const float* __restrict__ b17_0,
    const float* __restrict__ w17_1, const float* __restrict__ b17_1,
    const float* __restrict__ w111_0, const float* __restrict__ b111_0,
    const float* __restrict__ w111_1, const float* __restrict__ b111_1,
    const float* __restrict__ w211_0, const float* __restrict__ b211_0,
    const float* __restrict__ w211_1, const float* __restrict__ b211_1) {
  __shared__ float sm[SMEM_FLOATS];

  const int bid = blockIdx.x;
  const int pl = bid >> 3;
  const int t = bid & 7;
  const int tR0 = (t >> 2) * 64;
  const int tC0 = (t & 3) * 32;
  const int ch = pl & (CC - 1);
  const float* xp = x + (size_t)pl * PLANE;
  float* Tp = T + (size_t)pl * PLANE;
  const int tid = threadIdx.x;

  // ---- phase A: load raw x tile (rows -11..74, cols -12..43), zero OOB ----
  {
    float* xraw = sm + UNION_OFF;
    const int base_r = tR0 - 11, base_c = tC0 - 12;
    for (int i = tid; i < 86 * 14; i += 256) {
      int rr = i / 14;
      int jj = i - rr * 14;
      int gr = base_r + rr;
      int gc = base_c + jj * 4;
      float4 v = make_float4(0.f, 0.f, 0.f, 0.f);
      if ((unsigned)gr < 128u && (unsigned)gc < 128u)
        v = *(const float4*)(xp + gr * WW + gc);
      *(float4*)(xraw + rr * XRAW_STR + jj * 4) = v;
    }
  }
  __syncthreads();

  // ---- phase A2: U = x + avg3 + max3, rows -10..73, cols -10..41.
  // Row-fastest across lanes: transposed bf16 stores are lane-consecutive.
  {
    const float* xraw = sm + UNION_OFF;
    __hip_bfloat16* xsTh = (__hip_bfloat16*)(sm + XSTH_OFF);
    for (int i = tid; i < 84 * 13; i += 256) {
      int rr = i % 84;                   // xs row (tile row rr-10)
      int jj = i / 84;                   // col chunk: tile cols 4jj-10..+3
      const float* rp = xraw + rr * XRAW_STR + jj * 4;
      float4 a0 = *(const float4*)(rp);
      float4 a1 = *(const float4*)(rp + 4);
      float4 b0 = *(const float4*)(rp + XRAW_STR);
      float4 b1 = *(const float4*)(rp + XRAW_STR + 4);
      float4 c0 = *(const float4*)(rp + 2 * XRAW_STR);
      float4 c1 = *(const float4*)(rp + 2 * XRAW_STR + 4);
      float w0[8] = {a0.x, a0.y, a0.z, a0.w, a1.x, a1.y, a1.z, a1.w};
      float w1[8] = {b0.x, b0.y, b0.z, b0.w, b1.x, b1.y, b1.z, b1.w};
      float w2[8] = {c0.x, c0.y, c0.z, c0.w, c1.x, c1.y, c1.z, c1.w};
      int gr = tR0 + rr - 10;
      bool rv0 = (unsigned)(gr - 1) < 128u;
      bool rv1 = (unsigned)(gr) < 128u;
      bool rv2 = (unsigned)(gr + 1) < 128u;
      int gc0 = tC0 + jj * 4 - 12;
      float M0[8], M1[8], M2[8];
      #pragma unroll
      for (int p = 1; p <= 6; ++p) {
        bool cv = (unsigned)(gc0 + p) < 128u;
        M0[p] = (rv0 && cv) ? w0[p] : -3.402823466e38f;
        M1[p] = (rv1 && cv) ? w1[p] : -3.402823466e38f;
        M2[p] = (rv2 && cv) ? w2[p] : -3.402823466e38f;
      }
      float uq[4];
      #pragma unroll
      for (int q = 0; q < 4; ++q) {
        float s = w0[q + 1] + w0[q + 2] + w0[q + 3] + w1[q + 1] + w1[q + 2] +
                  w1[q + 3] + w2[q + 1] + w2[q + 2] + w2[q + 3];
        float m = fmaxf(
            fmaxf(fmaxf(M0[q + 1], M0[q + 2]), fmaxf(M0[q + 3], M1[q + 1])),
            fmaxf(fmaxf(M1[q + 2], M1[q + 3]),
                  fmaxf(fmaxf(M2[q + 1], M2[q + 2]), M2[q + 3])));
        float val = w1[q + 2] + s * (1.f / 9.f) + m;
        bool vo = rv1 && ((unsigned)(gc0 + q + 2) < 128u);
        uq[q] = vo ? val : 0.f;
      }
      *(float4*)(sm + XS_OFF + rr * XS_STR + jj * 4) =
          make_float4(uq[0], uq[1], uq[2], uq[3]);
      int rt = rr - 8;                   // xsT row (tile row -2..65)
      if ((unsigned)rt < 68u) {
        #pragma unroll
        for (int q = 0; q < 4; ++q) {
          int ct = jj * 4 + q - 8;       // xsT col (tile col -2..33 -> 0..35)
          if ((unsigned)ct < 36u)
            xsTh[ct * 72 + rt] = __float2bfloat16(uq[q]);
        }
      }
    }
  }

  float k7[7], k11[11], k21[21];
  #pragma unroll
  for (int i = 0; i < 7; ++i) k7[i] = w17_0[ch * 7 + i];
  #pragma unroll
  for (int i = 0; i < 11; ++i) k11[i] = w111_0[ch * 11 + i];
  #pragma unroll
  for (int i = 0; i < 21; ++i) k21[i] = w211_0[ch * 21 + i];
  float bb7 = 3.f * b17_0[ch];
  float bb11 = 3.f * b111_0[ch];
  float bb21 = 3.f * b211_0[ch];

  __syncthreads();

  // ---- phase B: horizontal convs; row-fastest lanes -> conflict-free
  // transposed stores ----
  for (int it = tid; it < 84 * 4; it += 256) {
    int rr = it % 84;
    int cg = it / 84;                    // output tile cols cg*8..+7
    float w[28];
    const float* xr = sm + XS_OFF + rr * XS_STR + cg * 8;
    #pragma unroll
    for (int j = 0; j < 7; ++j) {
      float4 v = *(const float4*)(xr + 4 * j);
      w[4 * j] = v.x; w[4 * j + 1] = v.y; w[4 * j + 2] = v.z; w[4 * j + 3] = v.w;
    }
    int gr = tR0 + rr - 10;
    bool rv = (unsigned)gr < 128u;
    bool v11r = (rr >= 5) && (rr <= 78);
    bool v7r = (rr >= 7) && (rr <= 76);
    #pragma unroll
    for (int j = 0; j < 8; ++j) {
      float a21 = bb21, a11 = bb11, a7 = bb7;
      #pragma unroll
      for (int d = 0; d < 21; ++d) a21 += k21[d] * w[j + d];
      #pragma unroll
      for (int d = 0; d < 11; ++d) a11 += k11[d] * w[j + 5 + d];
      #pragma unroll
      for (int d = 0; d < 7; ++d) a7 += k7[d] * w[j + 7 + d];
      int c = cg * 8 + j;
      sm[H21_OFF + c * H21_STR + rr] = rv ? a21 : 0.f;
      if (v11r) sm[H11_OFF + c * H11_STR + rr - 5] = rv ? a11 : 0.f;
      if (v7r) sm[H7_OFF + c * H7_STR + rr - 7] = rv ? a7 : 0.f;
    }
  }

  float v7a[7], v11a[11], v21a[21], w5a[25];
  #pragma unroll
  for (int i = 0; i < 7; ++i) v7a[i] = w17_1[ch * 7 + i];
  #pragma unroll
  for (int i = 0; i < 11; ++i) v11a[i] = w111_1[ch * 11 + i];
  #pragma unroll
  for (int i = 0; i < 21; ++i) v21a[i] = w211_1[ch * 21 + i];
  #pragma unroll
  for (int i = 0; i < 25; ++i) w5a[i] = w55[ch * 25 + i];
  float bsum = 3.f * (b55[ch] + b17_1[ch] + b111_1[ch] + b211_1[ch]);

  __syncthreads();

  // ---- phase C: vertical convs + 5x5; 8 rows per thread along a column ----
  {
    int c = tid & 31;
    int r0 = (tid >> 5) * 8;
    float acc[8];
    #pragma unroll
    for (int j = 0; j < 8; ++j) acc[j] = bsum;

    float A[28];
    {
      const float* hp = sm + H21_OFF + c * H21_STR + r0;
      #pragma unroll
      for (int j = 0; j < 7; ++j) {
        float4 v = *(const float4*)(hp + 4 * j);
        A[4 * j] = v.x; A[4 * j + 1] = v.y; A[4 * j + 2] = v.z; A[4 * j + 3] = v.w;
      }
      #pragma unroll
      for (int d = 0; d < 21; ++d)
        #pragma unroll
        for (int j = 0; j < 8; ++j) acc[j] += v21a[d] * A[d + j];
    }
    {
      const float* hp = sm + H11_OFF + c * H11_STR + r0;
      #pragma unroll
      for (int j = 0; j < 5; ++j) {
        float4 v = *(const float4*)(hp + 4 * j);
        A[4 * j] = v.x; A[4 * j + 1] = v.y; A[4 * j + 2] = v.z; A[4 * j + 3] = v.w;
      }
      #pragma unroll
      for (int d = 0; d < 11; ++d)
        #pragma unroll
        for (int j = 0; j < 8; ++j) acc[j] += v11a[d] * A[d + j];
    }
    {
      const float* hp = sm + H7_OFF + c * H7_STR + r0;
      #pragma unroll
      for (int j = 0; j < 4; ++j) {
        float4 v = *(const float4*)(hp + 4 * j);
        A[4 * j] = v.x; A[4 * j + 1] = v.y; A[4 * j + 2] = v.z; A[4 * j + 3] = v.w;
      }
      #pragma unroll
      for (int d = 0; d < 7; ++d)
        #pragma unroll
        for (int j = 0; j < 8; ++j) acc[j] += v7a[d] * A[d + j];
    }
    // 5x5 from bf16 transposed U
    {
      const unsigned int* xp32 = (const unsigned int*)(sm + XSTH_OFF);
      #pragma unroll
      for (int dc = 0; dc < 5; ++dc) {
        const unsigned int* hp = xp32 + (((c + dc) * 72 + r0) >> 1);
        uint4 u = *(const uint4*)hp;
        uint2 u2 = *(const uint2*)(hp + 4);
        float X[12];
        X[0] = lo16(u.x);  X[1] = hi16(u.x);
        X[2] = lo16(u.y);  X[3] = hi16(u.y);
        X[4] = lo16(u.z);  X[5] = hi16(u.z);
        X[6] = lo16(u.w);  X[7] = hi16(u.w);
        X[8] = lo16(u2.x); X[9] = hi16(u2.x);
        X[10] = lo16(u2.y); X[11] = hi16(u2.y);
        #pragma unroll
        for (int dr = 0; dr < 5; ++dr)
          #pragma unroll
          for (int j = 0; j < 8; ++j) acc[j] += w5a[dr * 5 + dc] * X[j + dr];
      }
    }
    #pragma unroll
    for (int j = 0; j < 8; ++j)
      Tp[(size_t)(tR0 + r0 + j) * WW + tC0 + c] = acc[j];
  }
}

// ---------------------------------------------------------------------------
// k_mix: out = (W11 . T + 3*b11) * x.  128 px x 64 co per block (2048 blocks),
// 4 px x 8 co per thread, 2-deep register ping-pong prefetch of T.
// ---------------------------------------------------------------------------
__global__ __launch_bounds__(256, 4) void k_mix(const float* __restrict__ T,
                                                const float* __restrict__ x,
                                                const float* __restrict__ w11,
                                                const float* __restrict__ b11,
                                                float* __restrict__ out) {
  __shared__ float Wt[64 * 68];            // [ci][co], stride 68
  int bid = blockIdx.x;
  int b = bid >> 7;
  int px0 = (bid & 127) * 128;
  int tid = threadIdx.x;

  for (int i = tid; i < 4096; i += 256) {
    int co = i >> 6, ci = i & 63;
    Wt[ci * 68 + co] = w11[i];
  }
  __syncthreads();

  int pxg = tid & 31;                      // 32 groups x 4 px
  int cog = tid >> 5;                      // 8 groups x 8 co
  const float* Tb = T + (size_t)b * (CC * PLANE) + px0 + pxg * 4;
  const float* wp = Wt + cog * 8;

  float acc[8][4];
  #pragma unroll
  for (int a = 0; a < 8; ++a)
    #pragma unroll
    for (int p = 0; p < 4; ++p) acc[a][p] = 0.f;

  float4 tb[2][4];
  #pragma unroll
  for (int kk = 0; kk < 4; ++kk)
    tb[0][kk] = *(const float4*)(Tb + (size_t)kk * PLANE);

  #pragma unroll
  for (int kc = 0; kc < 16; ++kc) {
    const int cur = kc & 1;
    if (kc < 15) {
      #pragma unroll
      for (int kk = 0; kk < 4; ++kk)
        tb[cur ^ 1][kk] =
            *(const float4*)(Tb + (size_t)((kc + 1) * 4 + kk) * PLANE);
    }
    #pragma unroll
    for (int kk = 0; kk < 4; ++kk) {
      int k = kc * 4 + kk;
      float4 q0 = *(const float4*)(wp + k * 68);
      float4 q1 = *(const float4*)(wp + k * 68 + 4);
      float wf[8] = {q0.x, q0.y, q0.z, q0.w, q1.x, q1.y, q1.z, q1.w};
      float4 tv = tb[cur][kk];
      float tvv[4] = {tv.x, tv.y, tv.z, tv.w};
      #pragma unroll
      for (int a = 0; a < 8; ++a)
        #pragma unroll
        for (int p = 0; p < 4; ++p) acc[a][p] += wf[a] * tvv[p];
    }
  }

  const float* xb = x + (size_t)b * (CC * PLANE) + px0 + pxg * 4;
  float* ob = out + (size_t)b * (CC * PLANE) + px0 + pxg * 4;
  #pragma unroll
  for (int a = 0; a < 8; ++a) {
    int co = cog * 8 + a;
    float bb = 3.f * b11[co];
    float4 xv = *(const float4*)(xb + (size_t)co * PLANE);
    float4 o;
    o.x = (acc[a][0] + bb) * xv.x;
    o.y = (acc[a][1] + bb) * xv.y;
    o.z = (acc[a][2] + bb) * xv.z;
    o.w = (acc[a][3] + bb) * xv.w;
    *(float4*)(ob + (size_t)co * PLANE) = o;
  }
}

extern "C" void kernel_launch(void* const* d_in, const int* in_sizes, int n_in,
                              void* d_out, int out_size, void* d_ws,
                              size_t ws_size, hipStream_t stream) {
  const float* x = (const float*)d_in[0];
  const float* w55 = (const float*)d_in[1];
  const float* b55 = (const float*)d_in[2];
  const float* w17_0 = (const float*)d_in[3];
  const float* b17_0 = (const float*)d_in[4];
  const float* w17_1 = (const float*)d_in[5];
  const float* b17_1 = (const float*)d_in[6];
  const float* w111_0 = (const float*)d_in[7];
  const float* b111_0 = (const float*)d_in[8];
  const float* w111_1 = (const float*)d_in[9];
  const float* b111_1 = (const float*)d_in[10];
  const float* w211_0 = (const float*)d_in[11];
  const float* b211_0 = (const float*)d_in[12];
  const float* w211_1 = (const float*)d_in[13];
  const float* b211_1 = (const float*)d_in[14];
  const float* w11 = (const float*)d_in[15];
  const float* b11 = (const float*)d_in[16];
  float* outp = (float*)d_out;

  float* T = (float*)d_ws;                 // [16,64,128,128]

  k_dwsum<<<BB * CC * 8, 256, 0, stream>>>(
      x, T, w55, b55, w17_0, b17_0, w17_1, b17_1, w111_0, b111_0, w111_1,
      b111_1, w211_0, b211_0, w211_1, b211_1);
  k_mix<<<BB * 128, 256, 0, stream>>>(T, x, w11, b11, outp);
}

// Round 4
// 303.105 us; speedup vs baseline: 1.5896x; 1.0114x over previous
//
#include <hip/hip_runtime.h>
#include <hip/hip_bf16.h>
#include <cstdint>

#define HH 128
#define WW 128
#define CC 64
#define BB 16
#define PLANE (HH*WW)
#define TPSTR 16512   // T plane stride: 16384 + 128 floats (512 B pad) breaks
                      // the 64-KB power-of-2 channel/set aliasing in k_mix.

// LDS layout. float strides chosen so lane-consecutive-index b128 accesses hit
// 8 distinct bank-start groups (stride*4 mod 128 = 4*odd): 52->20, 60->28,
// 88h=44f->12, 72h=36f->4.
//   xs   [84][52] f32  U row-major, rows -10..73, cols -10..41
//   xsTh [36][72] bf16 U col-major, cols -2..33, rows -2..65
//   h7T  [32][88] bf16 rows -3..66 (70 used)
//   union { xraw [86][60] f32 (phase A/A2) | h11T [32][88] bf16 rows -5..68 ;
//           h21T [32][88] bf16 rows -10..73 }
#define XS_STR    52
#define XRAW_STR  60
#define XSTH_H    8736    // half-index of xsTh   (= 4368 floats * 2)
#define H7_H      11328   // half-index of h7T    (= 5664 floats * 2)
#define UNION_F   7072    // float-index of xraw
#define H11_H     14144   // half-index of h11T   (inside union)
#define H21_H     16960   // half-index of h21T   (inside union)
#define SMEM_FLOATS 12232 // 48928 B -> 3 blocks/CU

__device__ __forceinline__ float lo16(unsigned int u) {
  return __uint_as_float(u << 16);
}
__device__ __forceinline__ float hi16(unsigned int u) {
  return __uint_as_float(u & 0xffff0000u);
}

__global__ __launch_bounds__(256, 3) void k_dwsum(
    const float* __restrict__ x, float* __restrict__ T,
    const float* __restrict__ w55, const float* __restrict__ b55,
    const float* __restrict__ w17_0, const float* __restrict__ b17_0,
    const float* __restrict__ w17_1, const float* __restrict__ b17_1,
    const float* __restrict__ w111_0, const float* __restrict__ b111_0,
    const float* __restrict__ w111_1, const float* __restrict__ b111_1,
    const float* __restrict__ w211_0, const float* __restrict__ b211_0,
    const float* __restrict__ w211_1, const float* __restrict__ b211_1) {
  __shared__ float sm[SMEM_FLOATS];
  __hip_bfloat16* hb = (__hip_bfloat16*)sm;

  const int bid = blockIdx.x;
  const int pl = bid >> 3;
  const int t = bid & 7;
  const int tR0 = (t >> 2) * 64;
  const int tC0 = (t & 3) * 32;
  const int ch = pl & (CC - 1);
  const float* xp = x + (size_t)pl * PLANE;
  float* Tp = T + (size_t)pl * TPSTR;
  const int tid = threadIdx.x;

  // ---- phase A: load raw x tile (rows -11..74, cols -12..43), zero OOB ----
  {
    float* xraw = sm + UNION_F;
    const int base_r = tR0 - 11, base_c = tC0 - 12;
    for (int i = tid; i < 86 * 14; i += 256) {
      int rr = i / 14;
      int jj = i - rr * 14;
      int gr = base_r + rr;
      int gc = base_c + jj * 4;
      float4 v = make_float4(0.f, 0.f, 0.f, 0.f);
      if ((unsigned)gr < 128u && (unsigned)gc < 128u)
        v = *(const float4*)(xp + gr * WW + gc);
      *(float4*)(xraw + rr * XRAW_STR + jj * 4) = v;
    }
  }
  __syncthreads();

  // ---- phase A2: U = x + avg3 + max3; 3 output rows per item (row reuse) --
  {
    const float* xraw = sm + UNION_F;
    __hip_bfloat16* xsTh = hb + XSTH_H;
    for (int i = tid; i < 28 * 13; i += 256) {
      int rg = i % 28;                   // lane-consecutive row group
      int jj = i / 28;
      int rr0 = rg * 3;                  // xs rows rr0..rr0+2
      const float* rp = xraw + rr0 * XRAW_STR + jj * 4;
      float w[5][8];
      #pragma unroll
      for (int k = 0; k < 5; ++k) {
        float4 a = *(const float4*)(rp + k * XRAW_STR);
        float4 b = *(const float4*)(rp + k * XRAW_STR + 4);
        w[k][0] = a.x; w[k][1] = a.y; w[k][2] = a.z; w[k][3] = a.w;
        w[k][4] = b.x; w[k][5] = b.y; w[k][6] = b.z; w[k][7] = b.w;
      }
      int gc0 = tC0 + jj * 4 - 12;
      bool cv[7];
      #pragma unroll
      for (int p = 1; p <= 6; ++p) cv[p] = (unsigned)(gc0 + p) < 128u;

      #pragma unroll
      for (int k = 0; k < 3; ++k) {
        int rr = rr0 + k;
        int gr = tR0 + rr - 10;
        bool rv0 = (unsigned)(gr - 1) < 128u;
        bool rv1 = (unsigned)(gr) < 128u;
        bool rv2 = (unsigned)(gr + 1) < 128u;
        float M0[7], M1[7], M2[7];
        #pragma unroll
        for (int p = 1; p <= 6; ++p) {
          M0[p] = (rv0 && cv[p]) ? w[k][p] : -3.402823466e38f;
          M1[p] = (rv1 && cv[p]) ? w[k + 1][p] : -3.402823466e38f;
          M2[p] = (rv2 && cv[p]) ? w[k + 2][p] : -3.402823466e38f;
        }
        float uq[4];
        #pragma unroll
        for (int q = 0; q < 4; ++q) {
          float s = w[k][q + 1] + w[k][q + 2] + w[k][q + 3] + w[k + 1][q + 1] +
                    w[k + 1][q + 2] + w[k + 1][q + 3] + w[k + 2][q + 1] +
                    w[k + 2][q + 2] + w[k + 2][q + 3];
          float m = fmaxf(
              fmaxf(fmaxf(M0[q + 1], M0[q + 2]), fmaxf(M0[q + 3], M1[q + 1])),
              fmaxf(fmaxf(M1[q + 2], M1[q + 3]),
                    fmaxf(fmaxf(M2[q + 1], M2[q + 2]), M2[q + 3])));
          float val = w[k + 1][q + 2] + s * (1.f / 9.f) + m;
          bool vo = rv1 && ((unsigned)(gc0 + q + 2) < 128u);
          uq[q] = vo ? val : 0.f;
        }
        *(float4*)(sm + rr * XS_STR + jj * 4) =
            make_float4(uq[0], uq[1], uq[2], uq[3]);
        int rt = rr - 8;                 // xsTh row (tile row -2..65)
        if ((unsigned)rt < 68u) {
          #pragma unroll
          for (int q = 0; q < 4; ++q) {
            int ct = jj * 4 + q - 8;     // xsTh col (tile col -2..33)
            if ((unsigned)ct < 36u)
              xsTh[ct * 72 + rt] = __float2bfloat16(uq[q]);
          }
        }
      }
    }
  }

  float k7[7], k11[11], k21[21];
  #pragma unroll
  for (int i = 0; i < 7; ++i) k7[i] = w17_0[ch * 7 + i];
  #pragma unroll
  for (int i = 0; i < 11; ++i) k11[i] = w111_0[ch * 11 + i];
  #pragma unroll
  for (int i = 0; i < 21; ++i) k21[i] = w211_0[ch * 21 + i];
  float bb7 = 3.f * b17_0[ch];
  float bb11 = 3.f * b111_0[ch];
  float bb21 = 3.f * b211_0[ch];

  __syncthreads();

  // ---- phase B: horizontal convs; bf16 transposed stores (lane-consec rr) --
  for (int it = tid; it < 84 * 4; it += 256) {
    int rr = it % 84;
    int cg = it / 84;                    // output tile cols cg*8..+7
    float w[28];
    const float* xr = sm + rr * XS_STR + cg * 8;
    #pragma unroll
    for (int j = 0; j < 7; ++j) {
      float4 v = *(const float4*)(xr + 4 * j);
      w[4 * j] = v.x; w[4 * j + 1] = v.y; w[4 * j + 2] = v.z; w[4 * j + 3] = v.w;
    }
    int gr = tR0 + rr - 10;
    bool rv = (unsigned)gr < 128u;
    bool v11r = (rr >= 5) && (rr <= 78);
    bool v7r = (rr >= 7) && (rr <= 76);
    #pragma unroll
    for (int j = 0; j < 8; ++j) {
      float a21 = bb21, a11 = bb11, a7 = bb7;
      #pragma unroll
      for (int d = 0; d < 21; ++d) a21 += k21[d] * w[j + d];
      #pragma unroll
      for (int d = 0; d < 11; ++d) a11 += k11[d] * w[j + 5 + d];
      #pragma unroll
      for (int d = 0; d < 7; ++d) a7 += k7[d] * w[j + 7 + d];
      int c = cg * 8 + j;
      hb[H21_H + c * 88 + rr] = __float2bfloat16(rv ? a21 : 0.f);
      if (v11r) hb[H11_H + c * 88 + rr - 5] = __float2bfloat16(rv ? a11 : 0.f);
      if (v7r) hb[H7_H + c * 88 + rr - 7] = __float2bfloat16(rv ? a7 : 0.f);
    }
  }

  float v7a[7], v11a[11], v21a[21], w5a[25];
  #pragma unroll
  for (int i = 0; i < 7; ++i) v7a[i] = w17_1[ch * 7 + i];
  #pragma unroll
  for (int i = 0; i < 11; ++i) v11a[i] = w111_1[ch * 11 + i];
  #pragma unroll
  for (int i = 0; i < 21; ++i) v21a[i] = w211_1[ch * 21 + i];
  #pragma unroll
  for (int i = 0; i < 25; ++i) w5a[i] = w55[ch * 25 + i];
  float bsum = 3.f * (b55[ch] + b17_1[ch] + b111_1[ch] + b211_1[ch]);

  __syncthreads();

  // ---- phase C: vertical convs + 5x5; 8 rows/thread along a column ----
  {
    int c = tid & 31;
    int r0 = (tid >> 5) * 8;
    float acc[8];
    #pragma unroll
    for (int j = 0; j < 8; ++j) acc[j] = bsum;

    float A[28];
    {  // h21: indices r0..r0+27 (28 halves)
      const unsigned* p = (const unsigned*)&hb[H21_H + c * 88 + r0];
      uint4 q0 = *(const uint4*)p;
      uint4 q1 = *(const uint4*)(p + 4);
      uint4 q2 = *(const uint4*)(p + 8);
      uint2 q3 = *(const uint2*)(p + 12);
      A[0]=lo16(q0.x);A[1]=hi16(q0.x);A[2]=lo16(q0.y);A[3]=hi16(q0.y);
      A[4]=lo16(q0.z);A[5]=hi16(q0.z);A[6]=lo16(q0.w);A[7]=hi16(q0.w);
      A[8]=lo16(q1.x);A[9]=hi16(q1.x);A[10]=lo16(q1.y);A[11]=hi16(q1.y);
      A[12]=lo16(q1.z);A[13]=hi16(q1.z);A[14]=lo16(q1.w);A[15]=hi16(q1.w);
      A[16]=lo16(q2.x);A[17]=hi16(q2.x);A[18]=lo16(q2.y);A[19]=hi16(q2.y);
      A[20]=lo16(q2.z);A[21]=hi16(q2.z);A[22]=lo16(q2.w);A[23]=hi16(q2.w);
      A[24]=lo16(q3.x);A[25]=hi16(q3.x);A[26]=lo16(q3.y);A[27]=hi16(q3.y);
      #pragma unroll
      for (int d = 0; d < 21; ++d)
        #pragma unroll
        for (int j = 0; j < 8; ++j) acc[j] += v21a[d] * A[d + j];
    }
    {  // h11: indices r0..r0+17 (18 halves, read 20)
      const unsigned* p = (const unsigned*)&hb[H11_H + c * 88 + r0];
      uint4 q0 = *(const uint4*)p;
      uint4 q1 = *(const uint4*)(p + 4);
      uint2 q2 = *(const uint2*)(p + 8);
      A[0]=lo16(q0.x);A[1]=hi16(q0.x);A[2]=lo16(q0.y);A[3]=hi16(q0.y);
      A[4]=lo16(q0.z);A[5]=hi16(q0.z);A[6]=lo16(q0.w);A[7]=hi16(q0.w);
      A[8]=lo16(q1.x);A[9]=hi16(q1.x);A[10]=lo16(q1.y);A[11]=hi16(q1.y);
      A[12]=lo16(q1.z);A[13]=hi16(q1.z);A[14]=lo16(q1.w);A[15]=hi16(q1.w);
      A[16]=lo16(q2.x);A[17]=hi16(q2.x);
      #pragma unroll
      for (int d = 0; d < 11; ++d)
        #pragma unroll
        for (int j = 0; j < 8; ++j) acc[j] += v11a[d] * A[d + j];
    }
    {  // h7: indices r0..r0+13 (14 halves, read 16)
      const unsigned* p = (const unsigned*)&hb[H7_H + c * 88 + r0];
      uint4 q0 = *(const uint4*)p;
      uint4 q1 = *(const uint4*)(p + 4);
      A[0]=lo16(q0.x);A[1]=hi16(q0.x);A[2]=lo16(q0.y);A[3]=hi16(q0.y);
      A[4]=lo16(q0.z);A[5]=hi16(q0.z);A[6]=lo16(q0.w);A[7]=hi16(q0.w);
      A[8]=lo16(q1.x);A[9]=hi16(q1.x);A[10]=lo16(q1.y);A[11]=hi16(q1.y);
      A[12]=lo16(q1.z);A[13]=hi16(q1.z);
      #pragma unroll
      for (int d = 0; d < 7; ++d)
        #pragma unroll
        for (int j = 0; j < 8; ++j) acc[j] += v7a[d] * A[d + j];
    }
    {  // 5x5 from bf16 transposed U: cols c..c+4, rows r0..r0+11
      #pragma unroll
      for (int dc = 0; dc < 5; ++dc) {
        const unsigned* p = (const unsigned*)&hb[XSTH_H + (c + dc) * 72 + r0];
        uint4 q0 = *(const uint4*)p;
        uint2 q1 = *(const uint2*)(p + 4);
        float X[12];
        X[0]=lo16(q0.x);X[1]=hi16(q0.x);X[2]=lo16(q0.y);X[3]=hi16(q0.y);
        X[4]=lo16(q0.z);X[5]=hi16(q0.z);X[6]=lo16(q0.w);X[7]=hi16(q0.w);
        X[8]=lo16(q1.x);X[9]=hi16(q1.x);X[10]=lo16(q1.y);X[11]=hi16(q1.y);
        #pragma unroll
        for (int dr = 0; dr < 5; ++dr)
          #pragma unroll
          for (int j = 0; j < 8; ++j) acc[j] += w5a[dr * 5 + dc] * X[j + dr];
      }
    }
    #pragma unroll
    for (int j = 0; j < 8; ++j)
      Tp[(size_t)(tR0 + r0 + j) * WW + tC0 + c] = acc[j];
  }
}

// ---------------------------------------------------------------------------
// k_mix: out = (W11 . T + 3*b11) * x.  T has padded plane stride TPSTR.
// 128 px x 64 co per block, 4 px x 8 co per thread, 3-slot (2-chunk-deep)
// register prefetch ring for T.
// ---------------------------------------------------------------------------
__global__ __launch_bounds__(256) void k_mix(const float* __restrict__ T,
                                             const float* __restrict__ x,
                                             const float* __restrict__ w11,
                                             const float* __restrict__ b11,
                                             float* __restrict__ out) {
  __shared__ float Wt[64 * 68];            // [ci][co], stride 68
  int bid = blockIdx.x;
  int b = bid >> 7;
  int px0 = (bid & 127) * 128;
  int tid = threadIdx.x;

  for (int i = tid; i < 4096; i += 256) {
    int co = i >> 6, ci = i & 63;
    Wt[ci * 68 + co] = w11[i];
  }
  __syncthreads();

  int pxg = tid & 31;                      // 32 groups x 4 px
  int cog = tid >> 5;                      // 8 groups x 8 co
  const float* Tb = T + (size_t)b * 64 * TPSTR + px0 + pxg * 4;
  const float* wp = Wt + cog * 8;

  float acc[8][4];
  #pragma unroll
  for (int a = 0; a < 8; ++a)
    #pragma unroll
    for (int p = 0; p < 4; ++p) acc[a][p] = 0.f;

  float4 tb[3][4];
  #pragma unroll
  for (int kk = 0; kk < 4; ++kk)
    tb[0][kk] = *(const float4*)(Tb + (size_t)kk * TPSTR);
  #pragma unroll
  for (int kk = 0; kk < 4; ++kk)
    tb[1][kk] = *(const float4*)(Tb + (size_t)(4 + kk) * TPSTR);

  #pragma unroll
  for (int kc = 0; kc < 16; ++kc) {
    const int cur = kc % 3;
    if (kc < 14) {
      const int nxt = (kc + 2) % 3;
      #pragma unroll
      for (int kk = 0; kk < 4; ++kk)
        tb[nxt][kk] =
            *(const float4*)(Tb + (size_t)((kc + 2) * 4 + kk) * TPSTR);
    }
    #pragma unroll
    for (int kk = 0; kk < 4; ++kk) {
      int k = kc * 4 + kk;
      float4 q0 = *(const float4*)(wp + k * 68);
      float4 q1 = *(const float4*)(wp + k * 68 + 4);
      float wf[8] = {q0.x, q0.y, q0.z, q0.w, q1.x, q1.y, q1.z, q1.w};
      float4 tv = tb[cur][kk];
      float tvv[4] = {tv.x, tv.y, tv.z, tv.w};
      #pragma unroll
      for (int a = 0; a < 8; ++a)
        #pragma unroll
        for (int p = 0; p < 4; ++p) acc[a][p] += wf[a] * tvv[p];
    }
  }

  const float* xb = x + (size_t)b * (CC * PLANE) + px0 + pxg * 4;
  float* ob = out + (size_t)b * (CC * PLANE) + px0 + pxg * 4;
  #pragma unroll
  for (int a = 0; a < 8; ++a) {
    int co = cog * 8 + a;
    float bb = 3.f * b11[co];
    float4 xv = *(const float4*)(xb + (size_t)co * PLANE);
    float4 o;
    o.x = (acc[a][0] + bb) * xv.x;
    o.y = (acc[a][1] + bb) * xv.y;
    o.z = (acc[a][2] + bb) * xv.z;
    o.w = (acc[a][3] + bb) * xv.w;
    *(float4*)(ob + (size_t)co * PLANE) = o;
  }
}

extern "C" void kernel_launch(void* const* d_in, const int* in_sizes, int n_in,
                              void* d_out, int out_size, void* d_ws,
                              size_t ws_size, hipStream_t stream) {
  const float* x = (const float*)d_in[0];
  const float* w55 = (const float*)d_in[1];
  const float* b55 = (const float*)d_in[2];
  const float* w17_0 = (const float*)d_in[3];
  const float* b17_0 = (const float*)d_in[4];
  const float* w17_1 = (const float*)d_in[5];
  const float* b17_1 = (const float*)d_in[6];
  const float* w111_0 = (const float*)d_in[7];
  const float* b111_0 = (const float*)d_in[8];
  const float* w111_1 = (const float*)d_in[9];
  const float* b111_1 = (const float*)d_in[10];
  const float* w211_0 = (const float*)d_in[11];
  const float* b211_0 = (const float*)d_in[12];
  const float* w211_1 = (const float*)d_in[13];
  const float* b211_1 = (const float*)d_in[14];
  const float* w11 = (const float*)d_in[15];
  const float* b11 = (const float*)d_in[16];
  float* outp = (float*)d_out;

  float* T = (float*)d_ws;                 // [16*64][TPSTR]

  k_dwsum<<<BB * CC * 8, 256, 0, stream>>>(
      x, T, w55, b55, w17_0, b17_0, w17_1, b17_1, w111_0, b111_0, w111_1,
      b111_1, w211_0, b211_0, w211_1, b211_1);
  k_mix<<<BB * 128, 256, 0, stream>>>(T, x, w11, b11, outp);
}